// Round 5
// baseline (1138.870 us; speedup 1.0000x reference)
//
#include <hip/hip_runtime.h>
#include <math.h>

#define BATCH 8
#define SEQ   2048
#define TOK   (BATCH*SEQ)     // 16384
#define CIN   32
#define DM    512
#define DFF   2048
#define NH    8
#define HD    64
#define NSAMP 24
#define NTOP  24
#define NSLAB 8
#define EPS   1e-5f
#define QKVLD 1536

typedef unsigned int u32;
typedef unsigned short u16;
typedef unsigned long long u64;
typedef __attribute__((ext_vector_type(8))) short short8;
typedef __attribute__((ext_vector_type(4))) short short4v;
typedef __attribute__((ext_vector_type(4))) float floatx4;

__device__ __forceinline__ void async16(const void* g, void* l) {
    __builtin_amdgcn_global_load_lds((const __attribute__((address_space(1))) u32*)g,
                                     (__attribute__((address_space(3))) u32*)l, 16, 0, 0);
}
__device__ __forceinline__ u16 bf16rn(float f) {
    u32 u = __float_as_uint(f);
    return (u16)((u + 0x7fffu + ((u >> 16) & 1u)) >> 16);
}
// separated-group format: per row of K elems, group g=j>>3 at u16 offset g*16: [h0..h7][l0..l7]
__device__ __forceinline__ void sep_store(u16* base, size_t row, int ld2, int j, float v) {
    u16 hb = bf16rn(v);
    float r = v - __uint_as_float((u32)hb << 16);
    size_t o = row * (size_t)ld2 + (size_t)((j >> 3) << 4) + (j & 7);
    base[o] = hb;
    base[o + 8] = bf16rn(r);
}
__device__ __forceinline__ float sep_load(const u16* base, size_t row, int ld2, int j) {
    size_t o = row * (size_t)ld2 + (size_t)((j >> 3) << 4) + (j & 7);
    return __uint_as_float((u32)base[o] << 16) + __uint_as_float((u32)base[o + 8] << 16);
}
__device__ __forceinline__ float hl2f(u16 h, u16 l) {
    return __uint_as_float((u32)h << 16) + __uint_as_float((u32)l << 16);
}

// ---------------- Threefry-2x32 ----------------
__device__ __forceinline__ void tf_round(unsigned &x0, unsigned &x1, int r) {
    x0 += x1;
    x1 = (x1 << r) | (x1 >> (32 - r));
    x1 ^= x0;
}
__device__ __forceinline__ void threefry(unsigned k0, unsigned k1,
                                         unsigned c0, unsigned c1,
                                         unsigned &o0, unsigned &o1) {
    unsigned ks0 = k0, ks1 = k1, ks2 = k0 ^ k1 ^ 0x1BD11BDAu;
    unsigned x0 = c0 + ks0, x1 = c1 + ks1;
    tf_round(x0,x1,13); tf_round(x0,x1,15); tf_round(x0,x1,26); tf_round(x0,x1,6);
    x0 += ks1; x1 += ks2 + 1u;
    tf_round(x0,x1,17); tf_round(x0,x1,29); tf_round(x0,x1,16); tf_round(x0,x1,24);
    x0 += ks2; x1 += ks0 + 2u;
    tf_round(x0,x1,13); tf_round(x0,x1,15); tf_round(x0,x1,26); tf_round(x0,x1,6);
    x0 += ks0; x1 += ks1 + 3u;
    tf_round(x0,x1,17); tf_round(x0,x1,29); tf_round(x0,x1,16); tf_round(x0,x1,24);
    x0 += ks1; x1 += ks2 + 4u;
    tf_round(x0,x1,13); tf_round(x0,x1,15); tf_round(x0,x1,26); tf_round(x0,x1,6);
    x0 += ks2; x1 += ks0 + 5u;
    o0 = x0; o1 = x1;
}

__global__ void sample_kernel(int* __restrict__ idx_sample) {
    const int HALF = (SEQ * NSAMP) / 2;  // 24576
    int p = blockIdx.x * blockDim.x + threadIdx.x;
    int li = blockIdx.y;
    if (p >= HALF) return;
    unsigned f0, f1;
    threefry(0u, 42u, 0u, (unsigned)li, f0, f1);
    unsigned a0, a1, b0, b1;
    threefry(f0, f1, 0u, 2u, a0, a1);
    threefry(f0, f1, 1u, 3u, b0, b1);
    unsigned o0, o1;
    threefry(a1, b1, (unsigned)p, (unsigned)(p + HALF), o0, o1);
    idx_sample[li * SEQ * NSAMP + p]        = (int)(o0 & (SEQ - 1));
    idx_sample[li * SEQ * NSAMP + p + HALF] = (int)(o1 & (SEQ - 1));
}

// ---------------- fused input-layernorm + im2col (wrap pad) -> separated u16 ----------
// 32 lanes per token (lane group = channel); each token scatters its LN'd row to the
// three (t,w) slots that reference it. Removes the xln round-trip entirely.
__global__ __launch_bounds__(256) void ln_im2col_kernel(const float* __restrict__ x,
        const float* __restrict__ g, const float* __restrict__ b, u16* __restrict__ a) {
    int sub = threadIdx.x >> 5;       // 0..7 (token within block)
    int c   = threadIdx.x & 31;       // channel
    int t = blockIdx.x * 8 + sub;     // global token
    int bb = t >> 11, l = t & 2047;
    float v = x[(size_t)t * CIN + c];
    float s = v;
#pragma unroll
    for (int m = 1; m <= 16; m <<= 1) s += __shfl_xor(s, m);
    float mean = s * (1.f / CIN);
    float d = v - mean;
    float vv = d * d;
#pragma unroll
    for (int m = 1; m <= 16; m <<= 1) vv += __shfl_xor(vv, m);
    float inv = rsqrtf(vv * (1.f / CIN) + EPS);
    float y = d * inv * g[c] + b[c];
    size_t base = (size_t)(bb << 11);
    sep_store(a, base + ((l + 1) & 2047), 192, c, y);        // w=0 slot
    sep_store(a, base + l,                192, 32 + c, y);   // w=1 slot
    sep_store(a, base + ((l - 1) & 2047), 192, 64 + c, y);   // w=2 slot
}

// ---------------- W_tok transpose + split: wt[o][j] separated ----------------
__global__ __launch_bounds__(256) void wtok_split(const float* __restrict__ Wtok,
        u16* __restrict__ wt) {
    int e = blockIdx.x * 256 + threadIdx.x;  // < 49152
    int o = e / 96, j = e % 96;
    sep_store(wt, (size_t)o, 192, j, Wtok[(size_t)j * DM + o]);
}

// ---------------- positional embedding table pe[l][o] ----------------
__global__ __launch_bounds__(256) void pe_kernel(float* __restrict__ pe) {
    int e = blockIdx.x * 256 + threadIdx.x;  // < 1048576
    int l = e >> 9, o = e & 511;
    const float c1 = -0.017988946039016f;  // -ln(10000)/512
    int i2 = o & ~1;
    float div = expf((float)i2 * c1);
    float arg = (float)l * div;
    pe[e] = (o & 1) ? cosf(arg) : sinf(arg);
}

// ---------------- rsd[t][o] = sep(pe[l][o] + tf[t]·Wtime[o]) ----------------
__global__ __launch_bounds__(256) void rsd_kernel(const float* __restrict__ pe,
        const float* __restrict__ tfeat, const float* __restrict__ Wtime,
        u16* __restrict__ rsd) {
    int t = blockIdx.x, tid = threadIdx.x;
    int l = t & 2047;
    float t0 = tfeat[(size_t)t * 4], t1 = tfeat[(size_t)t * 4 + 1];
    float t2 = tfeat[(size_t)t * 4 + 2], t3 = tfeat[(size_t)t * 4 + 3];
    for (int o = tid; o < DM; o += 256) {
        float v = pe[l * DM + o]
            + t0 * Wtime[o * 4] + t1 * Wtime[o * 4 + 1]
            + t2 * Wtime[o * 4 + 2] + t3 * Wtime[o * 4 + 3];
        sep_store(rsd, (size_t)t, 1024, o, v);
    }
}

// ---------------- weight split -> separated u16 buffers (+ fused bias concat) ----------
__global__ __launch_bounds__(256) void split_weights(const float* __restrict__ Wq,
        const float* __restrict__ Wk, const float* __restrict__ Wv,
        const float* __restrict__ Wo, const float* __restrict__ W1,
        const float* __restrict__ W2, u16* __restrict__ out,
        const float* __restrict__ bq, const float* __restrict__ bk,
        const float* __restrict__ bv, float* __restrict__ bqkv) {
    int i = blockIdx.x * 256 + threadIdx.x;  // < 3145728
    if (i < 1536)
        bqkv[i] = (i < 512) ? bq[i] : (i < 1024) ? bk[i - 512] : bv[i - 1024];
    if (i < 1048576) {
        const float* src = (i < 262144) ? Wq : (i < 524288) ? Wk : (i < 786432) ? Wv : Wo;
        int off = i & 262143;
        size_t base = (size_t)(i >> 18) * 524288;  // u16
        sep_store(out + base, (size_t)(off >> 9), 1024, off & 511, src[off]);
    } else if (i < 2097152) {
        int off = i - 1048576;
        sep_store(out + 2097152, (size_t)(off >> 9), 1024, off & 511, W1[off]);
    } else {
        int off = i - 2097152;
        sep_store(out + 4194304, (size_t)(off >> 11), 4096, off & 2047, W2[off]);
    }
}

// ---------------- separated-u16 MFMA GEMM, double-buffered single-barrier ------------
// 128x128 tile, 64 KiB LDS, 2 blocks/CU: inter-block overlap hides the barrier drain.
template<bool RELU, bool RESP, bool OUTP, bool OUTB>
__global__ __launch_bounds__(256, 2) void gemm_pp(const u16* __restrict__ Ap,
        const u16* __restrict__ Wp, const float* __restrict__ bias,
        const u16* __restrict__ RsdS, float* __restrict__ Cf, u16* __restrict__ Cp,
        int ldc, int K, int lda) {
    __shared__ alignas(16) u16 At[2][8192];   // [row 0..127][chunk 0..7][8 u16]
    __shared__ alignas(16) u16 Wt[2][8192];
    const int tid = threadIdx.x;
    int linear = blockIdx.y * gridDim.x + blockIdx.x;
    int xcd = linear & 7, sseq = linear >> 3;
    int mper = gridDim.y >> 3;
    int mt = xcd * mper + (sseq % mper);
    int nt = sseq / mper;
    const int m0 = mt * 128, n0 = nt * 128;
    const int lane = tid & 63, wv = tid >> 6;
    const int wm = wv >> 1, wn = wv & 1;
    const int fr = lane & 15, q = lane >> 4;

    floatx4 acc[4][4] = {};

    const int r0 = tid >> 3;
    const int gc = (tid & 7) ^ (r0 & 7);
    const u16* abase = Ap + (size_t)(m0 + r0) * (2 * lda) + gc * 8;
    const u16* wbase = Wp + (size_t)(n0 + r0) * (2 * K) + gc * 8;
    const size_t astep = (size_t)32 * 2 * lda;
    const size_t wstep = (size_t)32 * 2 * K;
    const int doff = tid * 16;
    const int nk = K >> 5;

    const int cph = ((q << 1) ^ (fr & 7)) << 3;
    const int cpl = ((q << 1) ^ (fr & 7) ^ 1) << 3;

#pragma unroll
    for (int i = 0; i < 4; i++) {
        async16(abase + i * astep, (char*)At[0] + doff + i * 4096);
        async16(wbase + i * wstep, (char*)Wt[0] + doff + i * 4096);
    }

    for (int k = 0; k < nk; k++) {
        const int b = k & 1;
        __syncthreads();
        if (k + 1 < nk) {
            int k2 = (k + 1) << 6;
#pragma unroll
            for (int i = 0; i < 4; i++) {
                async16(abase + k2 + i * astep, (char*)At[b ^ 1] + doff + i * 4096);
                async16(wbase + k2 + i * wstep, (char*)Wt[b ^ 1] + doff + i * 4096);
            }
        }
        short8 ah[4], al[4];
#pragma unroll
        for (int mi = 0; mi < 4; mi++) {
            int r = wm * 64 + mi * 16 + fr;
            ah[mi] = *(const short8*)&At[b][r * 64 + cph];
            al[mi] = *(const short8*)&At[b][r * 64 + cpl];
        }
#pragma unroll
        for (int ni = 0; ni < 4; ni++) {
            int r = wn * 64 + ni * 16 + fr;
            short8 wh8 = *(const short8*)&Wt[b][r * 64 + cph];
            short8 wl8 = *(const short8*)&Wt[b][r * 64 + cpl];
#pragma unroll
            for (int mi = 0; mi < 4; mi++) {
                acc[mi][ni] = __builtin_amdgcn_mfma_f32_16x16x32_bf16(ah[mi], wh8, acc[mi][ni], 0, 0, 0);
                acc[mi][ni] = __builtin_amdgcn_mfma_f32_16x16x32_bf16(ah[mi], wl8, acc[mi][ni], 0, 0, 0);
                acc[mi][ni] = __builtin_amdgcn_mfma_f32_16x16x32_bf16(al[mi], wh8, acc[mi][ni], 0, 0, 0);
            }
        }
    }
#pragma unroll
    for (int ni = 0; ni < 4; ni++) {
        int col = n0 + wn * 64 + ni * 16 + fr;
        float bv = bias[col];
#pragma unroll
        for (int mi = 0; mi < 4; mi++) {
            int row = m0 + wm * 64 + mi * 16 + q * 4;
#pragma unroll
            for (int r = 0; r < 4; r++) {
                float v = acc[mi][ni][r] + bv;
                if (RESP) v += sep_load(RsdS, (size_t)(row + r), 2 * ldc, col);
                if (RELU) v = fmaxf(v, 0.f);
                if (OUTP)      sep_store(Cp, (size_t)(row + r), 2 * ldc, col, v);
                else if (OUTB) Cp[(size_t)(row + r) * ldc + col] = bf16rn(v);
                else           Cf[(size_t)(row + r) * ldc + col] = v;
            }
        }
    }
}

// ---------------- single-bf16-A GEMM (2 MFMA/step): C = A*W^T + bias + sep-res --------
template<bool RELU, bool RESP>
__global__ __launch_bounds__(256, 2) void gemm_sb(const u16* __restrict__ Ab,
        const u16* __restrict__ Wp, const float* __restrict__ bias,
        const u16* __restrict__ RsdS, float* __restrict__ Cf,
        int ldc, int K, int lda) {
    __shared__ alignas(16) u16 At[2][4096];   // [kc 0..3][row 0..127][8 u16]
    __shared__ alignas(16) u16 Wt[2][8192];
    const int tid = threadIdx.x;
    int linear = blockIdx.y * gridDim.x + blockIdx.x;
    int xcd = linear & 7, sseq = linear >> 3;
    int mper = gridDim.y >> 3;
    int mt = xcd * mper + (sseq % mper);
    int nt = sseq / mper;
    const int m0 = mt * 128, n0 = nt * 128;
    const int lane = tid & 63, wv = tid >> 6;
    const int wm = wv >> 1, wn = wv & 1;
    const int fr = lane & 15, q = lane >> 4;

    floatx4 acc[4][4] = {};

    const int ar = tid & 127;
    const u16* abase = Ab + (size_t)(m0 + ar) * lda + (tid >> 7) * 8;
    const int adoff = tid * 16;   // byte, +i*4096
    const int r0 = tid >> 3;
    const int gc = (tid & 7) ^ (r0 & 7);
    const u16* wbase = Wp + (size_t)(n0 + r0) * (2 * K) + gc * 8;
    const size_t wstep = (size_t)32 * 2 * K;
    const int wdoff = tid * 16;
    const int nk = K >> 5;

    const int cph = ((q << 1) ^ (fr & 7)) << 3;
    const int cpl = ((q << 1) ^ (fr & 7) ^ 1) << 3;

#pragma unroll
    for (int i = 0; i < 2; i++)
        async16(abase + i * 16, (char*)At[0] + adoff + i * 4096);
#pragma unroll
    for (int i = 0; i < 4; i++)
        async16(wbase + i * wstep, (char*)Wt[0] + wdoff + i * 4096);

    for (int k = 0; k < nk; k++) {
        const int b = k & 1;
        __syncthreads();
        if (k + 1 < nk) {
            int ka = (k + 1) << 5;   // u16 elems
            int kw = (k + 1) << 6;
#pragma unroll
            for (int i = 0; i < 2; i++)
                async16(abase + ka + i * 16, (char*)At[b ^ 1] + adoff + i * 4096);
#pragma unroll
            for (int i = 0; i < 4; i++)
                async16(wbase + kw + i * wstep, (char*)Wt[b ^ 1] + wdoff + i * 4096);
        }
        short8 af[4];
#pragma unroll
        for (int mi = 0; mi < 4; mi++) {
            int r = wm * 64 + mi * 16 + fr;
            af[mi] = *(const short8*)&At[b][q * 1024 + r * 8];
        }
#pragma unroll
        for (int ni = 0; ni < 4; ni++) {
            int r = wn * 64 + ni * 16 + fr;
            short8 wh8 = *(const short8*)&Wt[b][r * 64 + cph];
            short8 wl8 = *(const short8*)&Wt[b][r * 64 + cpl];
#pragma unroll
            for (int mi = 0; mi < 4; mi++) {
                acc[mi][ni] = __builtin_amdgcn_mfma_f32_16x16x32_bf16(af[mi], wh8, acc[mi][ni], 0, 0, 0);
                acc[mi][ni] = __builtin_amdgcn_mfma_f32_16x16x32_bf16(af[mi], wl8, acc[mi][ni], 0, 0, 0);
            }
        }
    }
#pragma unroll
    for (int ni = 0; ni < 4; ni++) {
        int col = n0 + wn * 64 + ni * 16 + fr;
        float bv = bias[col];
#pragma unroll
        for (int mi = 0; mi < 4; mi++) {
            int row = m0 + wm * 64 + mi * 16 + q * 4;
#pragma unroll
            for (int r = 0; r < 4; r++) {
                float v = acc[mi][ni][r] + bv;
                if (RESP) v += sep_load(RsdS, (size_t)(row + r), 2 * ldc, col);
                if (RELU) v = fmaxf(v, 0.f);
                Cf[(size_t)(row + r) * ldc + col] = v;
            }
        }
    }
}

// ---------------- M = max(QK_sample) - sum/L : one wave per (b,h,l) ----------------
__global__ __launch_bounds__(256) void qk_sample_kernel(const float* __restrict__ qkv,
        const int* __restrict__ idx_sample, float* __restrict__ Mout) {
    int r = (blockIdx.x * 256 + threadIdx.x) >> 6;
    int lane = threadIdx.x & 63;
    if (r >= BATCH * NH * SEQ) return;
    int b = r / (NH * SEQ);
    int head = (r / SEQ) % NH;
    int l = r % SEQ;
    int sidx = lane >> 4, dc = lane & 15;
    const float* qrow = qkv + ((size_t)(b * SEQ + l)) * QKVLD + head * HD + dc * 4;
    float4 qf = *(const float4*)qrow;
    int myidx = (lane < NSAMP) ? idx_sample[l * NSAMP + lane] : 0;
    const float* kbase = qkv + (size_t)b * SEQ * QKVLD + 512 + head * HD + dc * 4;
    int kidx[6];
#pragma unroll
    for (int p = 0; p < 6; p++) kidx[p] = __shfl(myidx, p * 4 + sidx);
    float4 kf[6];
#pragma unroll
    for (int p = 0; p < 6; p++) kf[p] = *(const float4*)(kbase + (size_t)kidx[p] * QKVLD);
    float mx = -INFINITY, sm = 0.f;
#pragma unroll
    for (int p = 0; p < 6; p++) {
        float part = qf.x * kf[p].x + qf.y * kf[p].y + qf.z * kf[p].z + qf.w * kf[p].w;
        part += __shfl_xor(part, 1);
        part += __shfl_xor(part, 2);
        part += __shfl_xor(part, 4);
        part += __shfl_xor(part, 8);
        mx = fmaxf(mx, part);
        sm += part;
    }
    mx = fmaxf(mx, __shfl_xor(mx, 16));
    mx = fmaxf(mx, __shfl_xor(mx, 32));
    sm += __shfl_xor(sm, 16);
    sm += __shfl_xor(sm, 32);
    if (lane == 0) Mout[r] = mx - sm * (1.f / SEQ);
}

// ---------------- top-24: register keys + wave shuffle reduce ----------------
__device__ __forceinline__ u64 pack_key(float v, int idx) {
    u32 u = __float_as_uint(v);
    u32 m = (u & 0x80000000u) ? ~u : (u | 0x80000000u);
    return ((u64)m << 32) | (u32)(~(u32)idx);
}

__global__ __launch_bounds__(256) void topk_part(const float* __restrict__ Mbuf,
        u64* __restrict__ cand) {
    __shared__ u64 wred[4];
    int bh = blockIdx.x, chunk = blockIdx.y;
    int tid = threadIdx.x, wv = tid >> 6, lane = tid & 63;
    int l = chunk * 256 + tid;
    u64 val = pack_key(Mbuf[(size_t)bh * SEQ + l], l);
    for (int it = 0; it < NTOP; it++) {
        u64 w = val;
#pragma unroll
        for (int off = 32; off > 0; off >>= 1) {
            u64 o = __shfl_xor(w, off);
            if (o > w) w = o;
        }
        if (lane == 0) wred[wv] = w;
        __syncthreads();
        u64 win = wred[0];
        if (wred[1] > win) win = wred[1];
        if (wred[2] > win) win = wred[2];
        if (wred[3] > win) win = wred[3];
        if (val == win) val = 0;
        if (tid == 0) cand[((size_t)bh * 8 + chunk) * NTOP + it] = win;
        __syncthreads();
    }
}

// extended: also writes per-row head bitmask + u-slot map for the fused LN pass
__global__ __launch_bounds__(256) void topk_merge(const u64* __restrict__ cand,
        int* __restrict__ idx_top, u32* __restrict__ headmask, u16* __restrict__ umap) {
    __shared__ u64 wred[4];
    int bh = blockIdx.x;
    int tid = threadIdx.x, wv = tid >> 6, lane = tid & 63;
    u64 val = (tid < 8 * NTOP) ? cand[(size_t)bh * 8 * NTOP + tid] : 0;
    for (int it = 0; it < NTOP; it++) {
        u64 w = val;
#pragma unroll
        for (int off = 32; off > 0; off >>= 1) {
            u64 o = __shfl_xor(w, off);
            if (o > w) w = o;
        }
        if (lane == 0) wred[wv] = w;
        __syncthreads();
        u64 win = wred[0];
        if (wred[1] > win) win = wred[1];
        if (wred[2] > win) win = wred[2];
        if (wred[3] > win) win = wred[3];
        if (val == win) val = 0;
        if (tid == 0) {
            int row = (int)(~(u32)(win & 0xffffffffull) & (SEQ - 1));
            idx_top[bh * NTOP + it] = row;
            umap[(size_t)bh * SEQ + row] = (u16)it;
            atomicOr(&headmask[(((bh >> 3) << 11) | row)], 1u << (bh & 7));
        }
        __syncthreads();
    }
}

// ---------------- y_def[b][o] = bo[o] + sum_j Wo[o][j] * vmean_concat[b][j] (f32) ------
__global__ __launch_bounds__(512) void ydef_kernel(const float* __restrict__ Wo,
        const float* __restrict__ bo, const float* __restrict__ vmean,
        float* __restrict__ ydef) {
    __shared__ float vm[DM];
    int b = blockIdx.x, o = threadIdx.x;
    vm[o] = vmean[b * DM + o];    // vmean[bh][64] concat over h == [b][512]
    __syncthreads();
    const float* wr = Wo + (size_t)o * DM;
    float acc = bo[o];
    for (int j = 0; j < DM; j += 4) {
        float4 w4 = *(const float4*)&wr[j];
        acc += w4.x * vm[j] + w4.y * vm[j + 1] + w4.z * vm[j + 2] + w4.w * vm[j + 3];
    }
    ydef[b * DM + o] = acc;
}

// ---------------- compact Wo correction rows: corrRow[bh][u][o] = Wo_h·(upd-vmean) -----
__global__ __launch_bounds__(512) void corrRow_kernel(const float* __restrict__ Wo,
        const float* __restrict__ updC, const float* __restrict__ vmean,
        float* __restrict__ corrRow) {
    __shared__ float delta[NTOP][HD];
    int bh = blockIdx.x, h = bh & 7;
    int tid = threadIdx.x;
    for (int i = tid; i < NTOP * HD; i += 512) {
        int u = i >> 6, d = i & 63;
        delta[u][d] = updC[((size_t)bh * NTOP + u) * HD + d] - vmean[bh * HD + d];
    }
    __syncthreads();
    float w[HD];
    const float* wr = Wo + (size_t)tid * DM + h * HD;
#pragma unroll
    for (int d = 0; d < HD; d += 4) {
        float4 f = *(const float4*)&wr[d];
        w[d] = f.x; w[d + 1] = f.y; w[d + 2] = f.z; w[d + 3] = f.w;
    }
    for (int u = 0; u < NTOP; u++) {
        float acc = 0.f;
#pragma unroll
        for (int d = 0; d < HD; d++) acc += w[d] * delta[u][d];
        corrRow[((size_t)bh * NTOP + u) * DM + tid] = acc;
    }
}

// ---------------- fused: hf = sep(hp) + ydef + corr; LN; -> hp (sep). No hf trip. -----
__global__ __launch_bounds__(256) void resid_corr_ln(const u16* __restrict__ hp,
        const float* __restrict__ ydef, const float* __restrict__ corrRow,
        const u32* __restrict__ headmask, const u16* __restrict__ umap,
        const float* __restrict__ g, const float* __restrict__ b,
        u16* __restrict__ dstS) {
    int wv = threadIdx.x >> 6, lane = threadIdx.x & 63;
    int t = blockIdx.x * 4 + wv;
    int bb = t >> 11, l = t & 2047;
    const u16* sp = hp + (size_t)t * 1024 + (lane >> 1) * 16 + (lane & 1) * 4;
    short4v h0 = *(const short4v*)sp;
    short4v l0 = *(const short4v*)(sp + 8);
    short4v h1 = *(const short4v*)(sp + 512);
    short4v l1 = *(const short4v*)(sp + 520);
    int j0 = (lane >> 1) * 8 + (lane & 1) * 4;
    const float* yd = ydef + bb * DM;
    float4 y0 = *(const float4*)&yd[j0];
    float4 y1 = *(const float4*)&yd[j0 + 256];
    float xv[8];
    xv[0] = hl2f((u16)h0[0], (u16)l0[0]) + y0.x;
    xv[1] = hl2f((u16)h0[1], (u16)l0[1]) + y0.y;
    xv[2] = hl2f((u16)h0[2], (u16)l0[2]) + y0.z;
    xv[3] = hl2f((u16)h0[3], (u16)l0[3]) + y0.w;
    xv[4] = hl2f((u16)h1[0], (u16)l1[0]) + y1.x;
    xv[5] = hl2f((u16)h1[1], (u16)l1[1]) + y1.y;
    xv[6] = hl2f((u16)h1[2], (u16)l1[2]) + y1.z;
    xv[7] = hl2f((u16)h1[3], (u16)l1[3]) + y1.w;
    u32 mask = headmask[t];   // wave-uniform
    while (mask) {
        int h = __ffs(mask) - 1;
        mask &= mask - 1;
        int bh = bb * NH + h;
        int u = umap[(size_t)bh * SEQ + l];
        const float* cr = corrRow + ((size_t)bh * NTOP + u) * DM;
        float4 c0 = *(const float4*)&cr[j0];
        float4 c1 = *(const float4*)&cr[j0 + 256];
        xv[0] += c0.x; xv[1] += c0.y; xv[2] += c0.z; xv[3] += c0.w;
        xv[4] += c1.x; xv[5] += c1.y; xv[6] += c1.z; xv[7] += c1.w;
    }
    float s = 0.f, s2 = 0.f;
#pragma unroll
    for (int i = 0; i < 8; i++) { s += xv[i]; s2 += xv[i] * xv[i]; }
#pragma unroll
    for (int off = 32; off > 0; off >>= 1) {
        s  += __shfl_xor(s, off);
        s2 += __shfl_xor(s2, off);
    }
    float m = s * (1.f / DM);
    float var = s2 * (1.f / DM) - m * m;
    float inv = rsqrtf(var + EPS);
    float4 g0 = *(const float4*)&g[lane * 4];
    float4 g1 = *(const float4*)&g[lane * 4 + 256];
    float4 b0 = *(const float4*)&b[lane * 4];
    float4 b1 = *(const float4*)&b[lane * 4 + 256];
    float y[8];
    y[0] = (xv[0] - m) * inv * g0.x + b0.x;  y[1] = (xv[1] - m) * inv * g0.y + b0.y;
    y[2] = (xv[2] - m) * inv * g0.z + b0.z;  y[3] = (xv[3] - m) * inv * g0.w + b0.w;
    y[4] = (xv[4] - m) * inv * g1.x + b1.x;  y[5] = (xv[5] - m) * inv * g1.y + b1.y;
    y[6] = (xv[6] - m) * inv * g1.z + b1.z;  y[7] = (xv[7] - m) * inv * g1.w + b1.w;
    u16* dp = dstS + (size_t)t * 1024 + (lane >> 1) * 16 + (lane & 1) * 4;
    short4v hh0, ll0, hh1, ll1;
#pragma unroll
    for (int i = 0; i < 4; i++) {
        u16 hb = bf16rn(y[i]);
        hh0[i] = (short)hb;
        ll0[i] = (short)bf16rn(y[i] - __uint_as_float((u32)hb << 16));
        u16 hb2 = bf16rn(y[i + 4]);
        hh1[i] = (short)hb2;
        ll1[i] = (short)bf16rn(y[i + 4] - __uint_as_float((u32)hb2 << 16));
    }
    *(short4v*)dp = hh0;
    *(short4v*)(dp + 8) = ll0;
    *(short4v*)(dp + 512) = hh1;
    *(short4v*)(dp + 520) = ll1;
}

// ---------------- flash-style sparse attention + fused V-mean partials ----------------
__global__ __launch_bounds__(256) void spattn_flash(const float* __restrict__ qkv,
        const int* __restrict__ idx_top, float* __restrict__ opart,
        float* __restrict__ mspart, float* __restrict__ vmean) {
    __shared__ float KtT[64][65];   // transposed: [dim][key]
    __shared__ float Vt[64][65];    // [key][dim]
    __shared__ float Qs[24][64];
    __shared__ float Ps[24][66];
    __shared__ float vred[4][4][16];
    int bh = blockIdx.x, slab = blockIdx.y;
    int b = bh >> 3, h = bh & 7;
    int tid = threadIdx.x;
    int wv = tid >> 6, lane = tid & 63;
    for (int i = tid; i < NTOP * 64; i += 256) {
        int u = i >> 6, d = i & 63;
        int qi = idx_top[bh * NTOP + u];
        Qs[u][d] = qkv[((size_t)(b * SEQ + qi)) * QKVLD + h * HD + d];
    }
    float m[6], s[6], o[6], alpha[6];
#pragma unroll
    for (int j = 0; j < 6; j++) { m[j] = -INFINITY; s[j] = 0.f; o[j] = 0.f; }
    float vacc[16];
#pragma unroll
    for (int i = 0; i < 16; i++) vacc[i] = 0.f;
    int key0 = slab * (SEQ / NSLAB);
    int sr = tid >> 2, sc0 = (tid & 3) * 16;
    for (int t = 0; t < (SEQ / NSLAB) / 64; t++) {
        int kbase = key0 + t * 64;
        __syncthreads();
        const float* kr = qkv + ((size_t)(b * SEQ + kbase + sr)) * QKVLD + 512 + h * HD + sc0;
        const float* vr = qkv + ((size_t)(b * SEQ + kbase + sr)) * QKVLD + 1024 + h * HD + sc0;
        float kf[16], vf[16];
        *(float4*)&kf[0]  = *(const float4*)(kr);
        *(float4*)&kf[4]  = *(const float4*)(kr + 4);
        *(float4*)&kf[8]  = *(const float4*)(kr + 8);
        *(float4*)&kf[12] = *(const float4*)(kr + 12);
        *(float4*)&vf[0]  = *(const float4*)(vr);
        *(float4*)&vf[4]  = *(const float4*)(vr + 4);
        *(float4*)&vf[8]  = *(const float4*)(vr + 8);
        *(float4*)&vf[12] = *(const float4*)(vr + 12);
#pragma unroll
        for (int i = 0; i < 16; i++) {
            KtT[sc0 + i][sr] = kf[i];
            Vt[sr][sc0 + i] = vf[i];
            vacc[i] += vf[i];
        }
        __syncthreads();
        float dot[6] = {};
#pragma unroll
        for (int d = 0; d < 64; d++) {
            float kv = KtT[d][lane];
#pragma unroll
            for (int j = 0; j < 6; j++) dot[j] += Qs[wv * 6 + j][d] * kv;
        }
#pragma unroll
        for (int j = 0; j < 6; j++) {
            float sc = dot[j] * 0.125f;
            float tmax = sc;
            for (int off = 32; off > 0; off >>= 1) tmax = fmaxf(tmax, __shfl_xor(tmax, off));
            float mn = fmaxf(m[j], tmax);
            float p = __expf(sc - mn);
            float psum = p;
            for (int off = 32; off > 0; off >>= 1) psum += __shfl_xor(psum, off);
            alpha[j] = __expf(m[j] - mn);
            s[j] = s[j] * alpha[j] + psum;
            m[j] = mn;
            Ps[wv * 6 + j][lane] = p;
        }
        float pv[6] = {};
#pragma unroll
        for (int key = 0; key < 64; key++) {
            float vvv = Vt[key][lane];
#pragma unroll
            for (int j = 0; j < 6; j++) pv[j] += Ps[wv * 6 + j][key] * vvv;
        }
#pragma unroll
        for (int j = 0; j < 6; j++) o[j] = o[j] * alpha[j] + pv[j];
    }
    float* ob = opart + ((size_t)(bh * NSLAB + slab)) * NTOP * 64;
#pragma unroll
    for (int j = 0; j < 6; j++) ob[(wv * 6 + j) * 64 + lane] = o[j];
    if (lane == 0) {
        float* ms = mspart + ((size_t)(bh * NSLAB + slab)) * NTOP * 2;
#pragma unroll
        for (int j = 0; j < 6; j++) {
            ms[(wv * 6 + j) * 2]     = m[j];
            ms[(wv * 6 + j) * 2 + 1] = s[j];
        }
    }
    // fused V-mean slab partial: sum vacc over sr (lane bits 2..5 then cross-wave)
#pragma unroll
    for (int mm = 4; mm <= 32; mm <<= 1)
#pragma unroll
        for (int i = 0; i < 16; i++) vacc[i] += __shfl_xor(vacc[i], mm);
    if ((lane >> 2) == 0) {
#pragma unroll
        for (int i = 0; i < 16; i++) vred[wv][lane & 3][i] = vacc[i];
    }
    __syncthreads();
    if (tid < 64) {
        int g4 = tid >> 4, i = tid & 15;
        float s4 = vred[0][g4][i] + vred[1][g4][i] + vred[2][g4][i] + vred[3][g4][i];
        atomicAdd(&vmean[bh * HD + tid], s4 * (1.f / SEQ));
    }
}

// ---------------- merge slab partials -> compact f32 upd buffer ----------------
__global__ __launch_bounds__(256) void spattn_combine(const float* __restrict__ opart,
        const float* __restrict__ mspart, float* __restrict__ updC) {
    __shared__ float wgt[NSLAB][NTOP];
    int bh = blockIdx.x;
    int tid = threadIdx.x;
    if (tid < NTOP) {
        float mv[NSLAB], sv[NSLAB];
        float M = -INFINITY;
#pragma unroll
        for (int sl = 0; sl < NSLAB; sl++) {
            mv[sl] = mspart[((size_t)(bh * NSLAB + sl)) * NTOP * 2 + tid * 2];
            sv[sl] = mspart[((size_t)(bh * NSLAB + sl)) * NTOP * 2 + tid * 2 + 1];
            M = fmaxf(M, mv[sl]);
        }
        float S = 0.f;
#pragma unroll
        for (int sl = 0; sl < NSLAB; sl++) S += sv[sl] * __expf(mv[sl] - M);
        float invS = 1.f / S;
#pragma unroll
        for (int sl = 0; sl < NSLAB; sl++) wgt[sl][tid] = __expf(mv[sl] - M) * invS;
    }
    __syncthreads();
    for (int i = tid; i < NTOP * 64; i += 256) {
        int u = i >> 6, d = i & 63;
        float val = 0.f;
#pragma unroll
        for (int sl = 0; sl < NSLAB; sl++)
            val += wgt[sl][u] * opart[(((size_t)(bh * NSLAB + sl)) * NTOP + u) * 64 + d];
        updC[((size_t)bh * NTOP + u) * 64 + d] = val;
    }
}

// ---------------- layernorm over DM=512: one wave per row; sep in/out options ----------
template<bool INP, bool OUTSEP>
__global__ __launch_bounds__(256) void ln_kernel(const float* __restrict__ srcF,
        const u16* __restrict__ srcS, const float* __restrict__ g,
        const float* __restrict__ b, float* __restrict__ dstF, u16* __restrict__ dstS) {
    int wv = threadIdx.x >> 6, lane = threadIdx.x & 63;
    int t = blockIdx.x * 4 + wv;
    float xv[8];
    if (INP) {
        const u16* sp = srcS + (size_t)t * 1024 + (lane >> 1) * 16 + (lane & 1) * 4;
        short4v h0 = *(const short4v*)sp;
        short4v l0 = *(const short4v*)(sp + 8);
        short4v h1 = *(const short4v*)(sp + 512);
        short4v l1 = *(const short4v*)(sp + 520);
#pragma unroll
        for (int i = 0; i < 4; i++) {
            xv[i]     = hl2f((u16)h0[i], (u16)l0[i]);
            xv[i + 4] = hl2f((u16)h1[i], (u16)l1[i]);
        }
    } else {
        float4 x0 = *(const float4*)&srcF[(size_t)t * DM + lane * 4];
        float4 x1 = *(const float4*)&srcF[(size_t)t * DM + lane * 4 + 256];
        xv[0] = x0.x; xv[1] = x0.y; xv[2] = x0.z; xv[3] = x0.w;
        xv[4] = x1.x; xv[5] = x1.y; xv[6] = x1.z; xv[7] = x1.w;
    }
    float s = 0.f, s2 = 0.f;
#pragma unroll
    for (int i = 0; i < 8; i++) { s += xv[i]; s2 += xv[i] * xv[i]; }
#pragma unroll
    for (int off = 32; off > 0; off >>= 1) {
        s  += __shfl_xor(s, off);
        s2 += __shfl_xor(s2, off);
    }
    float m = s * (1.f / DM);
    float var = s2 * (1.f / DM) - m * m;
    float inv = rsqrtf(var + EPS);
    float4 g0 = *(const float4*)&g[lane * 4];
    float4 g1 = *(const float4*)&g[lane * 4 + 256];
    float4 b0 = *(const float4*)&b[lane * 4];
    float4 b1 = *(const float4*)&b[lane * 4 + 256];
    float y[8];
    y[0] = (xv[0] - m) * inv * g0.x + b0.x;  y[1] = (xv[1] - m) * inv * g0.y + b0.y;
    y[2] = (xv[2] - m) * inv * g0.z + b0.z;  y[3] = (xv[3] - m) * inv * g0.w + b0.w;
    y[4] = (xv[4] - m) * inv * g1.x + b1.x;  y[5] = (xv[5] - m) * inv * g1.y + b1.y;
    y[6] = (xv[6] - m) * inv * g1.z + b1.z;  y[7] = (xv[7] - m) * inv * g1.w + b1.w;
    if (OUTSEP) {
        u16* dp = dstS + (size_t)t * 1024 + (lane >> 1) * 16 + (lane & 1) * 4;
        short4v hh0, ll0, hh1, ll1;
#pragma unroll
        for (int i = 0; i < 4; i++) {
            u16 hb = bf16rn(y[i]);
            hh0[i] = (short)hb;
            ll0[i] = (short)bf16rn(y[i] - __uint_as_float((u32)hb << 16));
            u16 hb2 = bf16rn(y[i + 4]);
            hh1[i] = (short)hb2;
            ll1[i] = (short)bf16rn(y[i + 4] - __uint_as_float((u32)hb2 << 16));
        }
        *(short4v*)dp = hh0;
        *(short4v*)(dp + 8) = ll0;
        *(short4v*)(dp + 512) = hh1;
        *(short4v*)(dp + 520) = ll1;
    } else {
        float4 o0 = { y[0], y[1], y[2], y[3] };
        float4 o1 = { y[4], y[5], y[6], y[7] };
        *(float4*)&dstF[(size_t)t * DM + lane * 4] = o0;
        *(float4*)&dstF[(size_t)t * DM + lane * 4 + 256] = o1;
    }
}

// ---------------- prediction head on last token ----------------
__global__ __launch_bounds__(256) void head_kernel(const float* __restrict__ hfin,
        const float* __restrict__ Wpre, const float* __restrict__ bpre,
        const float* __restrict__ Wfc, const float* __restrict__ bfc,
        float* __restrict__ out) {
    __shared__ float last[DM];
    __shared__ float red[256];
    int b = blockIdx.x, tid = threadIdx.x;
    const float* hr = hfin + ((size_t)(b * SEQ + SEQ - 1)) * DM;
    last[tid] = hr[tid];
    last[tid + 256] = hr[tid + 256];
    __syncthreads();
    float acc = bpre[tid];
    for (int c = 0; c < DM; c++) acc += last[c] * Wpre[tid * DM + c];
    acc = fmaxf(acc, 0.f);
    red[tid] = acc * Wfc[tid];
    __syncthreads();
    for (int s = 128; s > 0; s >>= 1) { if (tid < s) red[tid] += red[tid + s]; __syncthreads(); }
    if (tid == 0) out[b] = red[0] + bfc[0];
}

extern "C" void kernel_launch(void* const* d_in, const int* in_sizes, int n_in,
                              void* d_out, int out_size, void* d_ws, size_t ws_size,
                              hipStream_t stream) {
    (void)in_sizes; (void)n_in; (void)out_size; (void)ws_size;
    const float* x      = (const float*)d_in[0];
    const float* tfeat  = (const float*)d_in[1];
    const float* g_in   = (const float*)d_in[2];
    const float* b_in   = (const float*)d_in[3];
    const float* W_tok  = (const float*)d_in[4];
    const float* W_time = (const float*)d_in[5];
    const float* b_time = (const float*)d_in[6];
    const float* Wq     = (const float*)d_in[7];
    const float* bq     = (const float*)d_in[8];
    const float* Wk     = (const float*)d_in[9];
    const float* bk     = (const float*)d_in[10];
    const float* Wv     = (const float*)d_in[11];
    const float* bv     = (const float*)d_in[12];
    const float* Wo     = (const float*)d_in[13];
    const float* bo     = (const float*)d_in[14];
    const float* W1     = (const float*)d_in[15];
    const float* b1     = (const float*)d_in[16];
    const float* W2     = (const float*)d_in[17];
    const float* b2     = (const float*)d_in[18];
    const float* g1     = (const float*)d_in[19];
    const float* be1    = (const float*)d_in[20];
    const float* g2     = (const float*)d_in[21];
    const float* be2    = (const float*)d_in[22];
    const float* g_enc  = (const float*)d_in[23];
    const float* b_enc  = (const float*)d_in[24];
    const float* W_pre  = (const float*)d_in[25];
    const float* b_pre  = (const float*)d_in[26];
    const float* W_fc   = (const float*)d_in[27];
    const float* b_fc   = (const float*)d_in[28];
    float* out = (float*)d_out;

    char* ws = (char*)d_ws;
    u16*   hp   = (u16*)(ws);                        // 33.5 MB residual stream (separated)
    float* hf   = (float*)(ws + 33554432);           // 33.5 MB fp32 scratch
    char*  bigc = ws + 67108864;                     // 134.2 MB multi-use
    float* qkv  = (float*)bigc;                      // [TOK][1536] fp32 (100.7 MB)
    u16*   midP = (u16*)bigc;                        // FFN mid separated (layer 1)
    u16*   midB = (u16*)bigc;                        // FFN mid plain bf16 (layer 2, 67 MB)
    // attention scratch beyond qkv's 100.7 MB:
    float* updC    = (float*)(bigc + 100663296);     // [64][24][64] f32 (393 KB)
    float* ydefb   = (float*)(bigc + 101056512);     // [8][512] f32 (16 KB)
    float* opart   = (float*)(bigc + 101072896);     // [64][8][24][64] f32 (3.1 MB)
    float* mspart  = (float*)(bigc + 104218624);     // [64][8][24][2] f32 (96 KB)
    float* corrRow = (float*)(bigc + 104316928);     // [64][24][512] f32 (3.1 MB)
    float* vmeanN  = (float*)(bigc + 107462656);     // [64][64] f32 (16 KB)
    u32*   headmask= (u32*)(bigc + 107479040);       // [TOK] u32 (64 KB)  [contiguous w/ vmeanN]
    u16*   umap    = (u16*)(bigc + 107544576);       // [64][2048] u16 (256 KB, no clear needed)
    // embed-stage overlays inside bigc:
    u16*   acvP = (u16*)(bigc + 2097152);            // im2col separated [TOK][192] u16
    float* pe   = (float*)(bigc + 8388608);          // 4 MB
    u16*   rsdS = (u16*)(bigc + 12582912);           // 33.5 MB
    u16*   wtok = (u16*)(bigc + 46137344);           // W_tok separated [512][192] u16
    u16*   wsep       = (u16*)(ws + 201326592);      // 12.6 MB per-layer weights
    float* Mbuf       = (float*)(ws + 213909504);    // 0.5 MB
    int*   idx_sample = (int*)(ws + 214450176);
    int*   idx_top    = (int*)(ws + 214843392);
    float* biasqkv    = (float*)(ws + 214849536);
    u64*   cand       = (u64*)(ws + 214855680);      // 98 KB

    ln_im2col_kernel<<<TOK / 8, 256, 0, stream>>>(x, g_in, b_in, acvP);
    wtok_split<<<192, 256, 0, stream>>>(W_tok, wtok);
    pe_kernel<<<4096, 256, 0, stream>>>(pe);
    rsd_kernel<<<TOK, 256, 0, stream>>>(pe, tfeat, W_time, rsdS);
    sample_kernel<<<dim3(96, 2), 256, 0, stream>>>(idx_sample);

    // conv-as-GEMM: hp = sep(im2col @ W_tok^T + b_time + (pe + time emb))
    gemm_pp<false, true, true, false><<<dim3(4, 128), 256, 0, stream>>>(
        acvP, wtok, b_time, rsdS, nullptr, hp, DM, 96, 96);

    const u16* wqkv_p = wsep;                 // rows 0..1535 = Wq;Wk;Wv (K=512)
    const u16* w1_p = wsep + 2097152;
    const u16* w2_p = wsep + 4194304;

    for (int li = 0; li < 2; li++) {
        split_weights<<<12288, 256, 0, stream>>>(
            Wq + (size_t)li * DM * DM, Wk + (size_t)li * DM * DM,
            Wv + (size_t)li * DM * DM, Wo + (size_t)li * DM * DM,
            W1 + (size_t)li * DFF * DM, W2 + (size_t)li * DM * DFF, wsep,
            bq + (size_t)li * DM, bk + (size_t)li * DM, bv + (size_t)li * DM, biasqkv);

        const float* Wo_i = Wo + (size_t)li * DM * DM;
        const float* bo_i = bo + (size_t)li * DM;
        const float* b1_i = b1 + (size_t)li * DFF;
        const float* b2_i = b2 + (size_t)li * DM;
        const float* g1_i = g1 + (size_t)li * DM;
        const float* be1_i = be1 + (size_t)li * DM;
        const float* g2_i = g2 + (size_t)li * DM;
        const float* be2_i = be2 + (size_t)li * DM;

        // fused QKV: [TOK][1536] fp32
        gemm_pp<false, false, false, false><<<dim3(QKVLD / 128, TOK / 128), 256, 0, stream>>>(
            hp, wqkv_p, biasqkv, nullptr, qkv, nullptr, QKVLD, DM, DM);

        qk_sample_kernel<<<(BATCH * NH * SEQ) / 4, 256, 0, stream>>>(
            qkv, idx_sample + li * SEQ * NSAMP, Mbuf);
        topk_part<<<dim3(BATCH * NH, 8), 256, 0, stream>>>(Mbuf, cand);
        hipMemsetAsync(vmeanN, 0, 16384 + 65536, stream);   // vmeanN + headmask (contiguous)
        topk_merge<<<BATCH * NH, 256, 0, stream>>>(cand, idx_top, headmask, umap);
        spattn_flash<<<dim3(BATCH * NH, NSLAB), 256, 0, stream>>>(
            qkv, idx_top, opart, mspart, vmeanN);
        spattn_combine<<<BATCH * NH, 256, 0, stream>>>(opart, mspart, updC);
        ydef_kernel<<<BATCH, 512, 0, stream>>>(Wo_i, bo_i, vmeanN, ydefb);
        corrRow_kernel<<<BATCH * NH, 512, 0, stream>>>(Wo_i, updC, vmeanN, corrRow);

        // fused: residual + Wo-default + sparse corr + LN1 -> hp (no hf round-trip)
        resid_corr_ln<<<TOK / 4, 256, 0, stream>>>(
            hp, ydefb, corrRow, headmask, umap, g1_i, be1_i, hp);

        if (li == 0) {
            // layer-1 FFN: full-precision mid (protects layer-2 ProbSparse selection)
            gemm_pp<true, false, true, false><<<dim3(DFF / 128, TOK / 128), 256, 0, stream>>>(
                hp, w1_p, b1_i, nullptr, nullptr, midP, DFF, DM, DM);
            gemm_pp<false, true, false, false><<<dim3(DM / 128, TOK / 128), 256, 0, stream>>>(
                midP, w2_p, b2_i, hp, hf, nullptr, DM, DFF, DFF);
        } else {
            // layer-2 FFN: plain-bf16 mid (output path only; 2-MFMA W2)
            gemm_pp<true, false, false, true><<<dim3(DFF / 128, TOK / 128), 256, 0, stream>>>(
                hp, w1_p, b1_i, nullptr, nullptr, midB, DFF, DM, DM);
            gemm_sb<false, true><<<dim3(DM / 128, TOK / 128), 256, 0, stream>>>(
                midB, w2_p, b2_i, hp, hf, DM, DFF, DFF);
        }
        ln_kernel<false, true><<<TOK / 4, 256, 0, stream>>>(hf, nullptr, g2_i, be2_i, nullptr, hp);
    }

    ln_kernel<true, false><<<TOK / 4, 256, 0, stream>>>(nullptr, hp, g_enc, b_enc, hf, nullptr);
    head_kernel<<<BATCH, 256, 0, stream>>>(hf, W_pre, b_pre, W_fc, b_fc, out);
}

// Round 6
// 1105.734 us; speedup vs baseline: 1.0300x; 1.0300x over previous
//
#include <hip/hip_runtime.h>
#include <math.h>

#define BATCH 8
#define SEQ   2048
#define TOK   (BATCH*SEQ)     // 16384
#define CIN   32
#define DM    512
#define DFF   2048
#define NH    8
#define HD    64
#define NSAMP 24
#define NTOP  24
#define EPS   1e-5f
#define QKVLD 1536

typedef unsigned int u32;
typedef unsigned short u16;
typedef unsigned long long u64;
typedef __attribute__((ext_vector_type(8))) short short8;
typedef __attribute__((ext_vector_type(4))) short short4v;
typedef __attribute__((ext_vector_type(4))) float floatx4;

__device__ __forceinline__ void async16(const void* g, void* l) {
    __builtin_amdgcn_global_load_lds((const __attribute__((address_space(1))) u32*)g,
                                     (__attribute__((address_space(3))) u32*)l, 16, 0, 0);
}
__device__ __forceinline__ u16 bf16rn(float f) {
    u32 u = __float_as_uint(f);
    return (u16)((u + 0x7fffu + ((u >> 16) & 1u)) >> 16);
}
// separated-group format: per row of K elems, group g=j>>3 at u16 offset g*16: [h0..h7][l0..l7]
__device__ __forceinline__ void sep_store(u16* base, size_t row, int ld2, int j, float v) {
    u16 hb = bf16rn(v);
    float r = v - __uint_as_float((u32)hb << 16);
    size_t o = row * (size_t)ld2 + (size_t)((j >> 3) << 4) + (j & 7);
    base[o] = hb;
    base[o + 8] = bf16rn(r);
}
__device__ __forceinline__ float sep_load(const u16* base, size_t row, int ld2, int j) {
    size_t o = row * (size_t)ld2 + (size_t)((j >> 3) << 4) + (j & 7);
    return __uint_as_float((u32)base[o] << 16) + __uint_as_float((u32)base[o + 8] << 16);
}
__device__ __forceinline__ float hl2f(u16 h, u16 l) {
    return __uint_as_float((u32)h << 16) + __uint_as_float((u32)l << 16);
}

// ---------------- Threefry-2x32 ----------------
__device__ __forceinline__ void tf_round(unsigned &x0, unsigned &x1, int r) {
    x0 += x1;
    x1 = (x1 << r) | (x1 >> (32 - r));
    x1 ^= x0;
}
__device__ __forceinline__ void threefry(unsigned k0, unsigned k1,
                                         unsigned c0, unsigned c1,
                                         unsigned &o0, unsigned &o1) {
    unsigned ks0 = k0, ks1 = k1, ks2 = k0 ^ k1 ^ 0x1BD11BDAu;
    unsigned x0 = c0 + ks0, x1 = c1 + ks1;
    tf_round(x0,x1,13); tf_round(x0,x1,15); tf_round(x0,x1,26); tf_round(x0,x1,6);
    x0 += ks1; x1 += ks2 + 1u;
    tf_round(x0,x1,17); tf_round(x0,x1,29); tf_round(x0,x1,16); tf_round(x0,x1,24);
    x0 += ks2; x1 += ks0 + 2u;
    tf_round(x0,x1,13); tf_round(x0,x1,15); tf_round(x0,x1,26); tf_round(x0,x1,6);
    x0 += ks0; x1 += ks1 + 3u;
    tf_round(x0,x1,17); tf_round(x0,x1,29); tf_round(x0,x1,16); tf_round(x0,x1,24);
    x0 += ks1; x1 += ks2 + 4u;
    tf_round(x0,x1,13); tf_round(x0,x1,15); tf_round(x0,x1,26); tf_round(x0,x1,6);
    x0 += ks2; x1 += ks0 + 5u;
    o0 = x0; o1 = x1;
}

__global__ void sample_kernel(int* __restrict__ idx_sample) {
    const int HALF = (SEQ * NSAMP) / 2;  // 24576
    int p = blockIdx.x * blockDim.x + threadIdx.x;
    int li = blockIdx.y;
    if (p >= HALF) return;
    unsigned f0, f1;
    threefry(0u, 42u, 0u, (unsigned)li, f0, f1);
    unsigned a0, a1, b0, b1;
    threefry(f0, f1, 0u, 2u, a0, a1);
    threefry(f0, f1, 1u, 3u, b0, b1);
    unsigned o0, o1;
    threefry(a1, b1, (unsigned)p, (unsigned)(p + HALF), o0, o1);
    idx_sample[li * SEQ * NSAMP + p]        = (int)(o0 & (SEQ - 1));
    idx_sample[li * SEQ * NSAMP + p + HALF] = (int)(o1 & (SEQ - 1));
}

// ---------------- input layernorm over C_IN=32 ----------------
__global__ __launch_bounds__(256) void ln_in_kernel(const float* __restrict__ x,
        const float* __restrict__ g, const float* __restrict__ b,
        float* __restrict__ out) {
    int t = blockIdx.x * blockDim.x + threadIdx.x;
    if (t >= TOK) return;
    const float* xr = x + (size_t)t * CIN;
    float vals[CIN];
    float s = 0.f;
#pragma unroll
    for (int c = 0; c < CIN; c++) { vals[c] = xr[c]; s += vals[c]; }
    float m = s * (1.f / CIN);
    float v = 0.f;
#pragma unroll
    for (int c = 0; c < CIN; c++) { float d = vals[c] - m; v += d * d; }
    v *= (1.f / CIN);
    float inv = rsqrtf(v + EPS);
    float* orow = out + (size_t)t * CIN;
#pragma unroll
    for (int c = 0; c < CIN; c++) orow[c] = (vals[c] - m) * inv * g[c] + b[c];
}

// ---------------- im2col (wrap pad) -> separated u16: A[t][j], j=w*32+c ----------------
__global__ __launch_bounds__(128) void im2col_kernel(const float* __restrict__ xln,
        u16* __restrict__ a) {
    int t = blockIdx.x;
    int j = threadIdx.x;
    if (j >= 96) return;
    int b = t >> 11, l = t & 2047;
    int w = j >> 5, c = j & 31;
    int lw = (l - 1 + w + SEQ) & 2047;
    sep_store(a, (size_t)t, 192, j, xln[(((size_t)b << 11) | lw) * CIN + c]);
}

// ---------------- W_tok transpose + split: wt[o][j] separated ----------------
__global__ __launch_bounds__(256) void wtok_split(const float* __restrict__ Wtok,
        u16* __restrict__ wt) {
    int e = blockIdx.x * 256 + threadIdx.x;  // < 49152
    int o = e / 96, j = e % 96;
    sep_store(wt, (size_t)o, 192, j, Wtok[(size_t)j * DM + o]);
}

// ---------------- positional embedding table pe[l][o] ----------------
__global__ __launch_bounds__(256) void pe_kernel(float* __restrict__ pe) {
    int e = blockIdx.x * 256 + threadIdx.x;  // < 1048576
    int l = e >> 9, o = e & 511;
    const float c1 = -0.017988946039016f;  // -ln(10000)/512
    int i2 = o & ~1;
    float div = expf((float)i2 * c1);
    float arg = (float)l * div;
    pe[e] = (o & 1) ? cosf(arg) : sinf(arg);
}

// ---------------- rsd[t][o] = sep(pe[l][o] + tf[t]·Wtime[o]) ----------------
__global__ __launch_bounds__(256) void rsd_kernel(const float* __restrict__ pe,
        const float* __restrict__ tfeat, const float* __restrict__ Wtime,
        u16* __restrict__ rsd) {
    int t = blockIdx.x, tid = threadIdx.x;
    int l = t & 2047;
    float t0 = tfeat[(size_t)t * 4], t1 = tfeat[(size_t)t * 4 + 1];
    float t2 = tfeat[(size_t)t * 4 + 2], t3 = tfeat[(size_t)t * 4 + 3];
    for (int o = tid; o < DM; o += 256) {
        float v = pe[l * DM + o]
            + t0 * Wtime[o * 4] + t1 * Wtime[o * 4 + 1]
            + t2 * Wtime[o * 4 + 2] + t3 * Wtime[o * 4 + 3];
        sep_store(rsd, (size_t)t, 1024, o, v);
    }
}

// ---------------- weight split -> separated u16 buffers (+ fused bias concat) ----------
__global__ __launch_bounds__(256) void split_weights(const float* __restrict__ Wq,
        const float* __restrict__ Wk, const float* __restrict__ Wv,
        const float* __restrict__ Wo, const float* __restrict__ W1,
        const float* __restrict__ W2, u16* __restrict__ out,
        const float* __restrict__ bq, const float* __restrict__ bk,
        const float* __restrict__ bv, float* __restrict__ bqkv) {
    int i = blockIdx.x * 256 + threadIdx.x;  // < 3145728
    if (i < 1536)
        bqkv[i] = (i < 512) ? bq[i] : (i < 1024) ? bk[i - 512] : bv[i - 1024];
    if (i < 1048576) {
        const float* src = (i < 262144) ? Wq : (i < 524288) ? Wk : (i < 786432) ? Wv : Wo;
        int off = i & 262143;
        size_t base = (size_t)(i >> 18) * 524288;  // u16
        sep_store(out + base, (size_t)(off >> 9), 1024, off & 511, src[off]);
    } else if (i < 2097152) {
        int off = i - 1048576;
        sep_store(out + 2097152, (size_t)(off >> 9), 1024, off & 511, W1[off]);
    } else {
        int off = i - 2097152;
        sep_store(out + 4194304, (size_t)(off >> 11), 4096, off & 2047, W2[off]);
    }
}

// ---------------- separated-u16 MFMA GEMM, double-buffered single-barrier ------------
// 128x128 tile, 64 KiB LDS, 2 blocks/CU (measured-best structure, ~908 TF effective).
// NM=3: full pair precision (ah*wh + ah*wl + al*wh) — selection-critical paths.
// NM=2: drop al*wh (A_lo dropped; ~2^-9 rel error) — output-path-only GEMMs whose
//       result is anyway quantized to bf16 (2^-8) downstream.
template<int NM, bool RELU, bool RESP, bool OUTP, bool OUTB>
__global__ __launch_bounds__(256, 2) void gemm_pp(const u16* __restrict__ Ap,
        const u16* __restrict__ Wp, const float* __restrict__ bias,
        const u16* __restrict__ RsdS, float* __restrict__ Cf, u16* __restrict__ Cp,
        int ldc, int K, int lda) {
    __shared__ alignas(16) u16 At[2][8192];   // [row 0..127][chunk 0..7][8 u16]
    __shared__ alignas(16) u16 Wt[2][8192];
    const int tid = threadIdx.x;
    int linear = blockIdx.y * gridDim.x + blockIdx.x;
    int xcd = linear & 7, sseq = linear >> 3;
    int mper = gridDim.y >> 3;
    int mt = xcd * mper + (sseq % mper);
    int nt = sseq / mper;
    const int m0 = mt * 128, n0 = nt * 128;
    const int lane = tid & 63, wv = tid >> 6;
    const int wm = wv >> 1, wn = wv & 1;
    const int fr = lane & 15, q = lane >> 4;

    floatx4 acc[4][4] = {};

    const int r0 = tid >> 3;
    const int gc = (tid & 7) ^ (r0 & 7);
    const u16* abase = Ap + (size_t)(m0 + r0) * (2 * lda) + gc * 8;
    const u16* wbase = Wp + (size_t)(n0 + r0) * (2 * K) + gc * 8;
    const size_t astep = (size_t)32 * 2 * lda;
    const size_t wstep = (size_t)32 * 2 * K;
    const int doff = tid * 16;
    const int nk = K >> 5;

    const int cph = ((q << 1) ^ (fr & 7)) << 3;
    const int cpl = ((q << 1) ^ (fr & 7) ^ 1) << 3;

#pragma unroll
    for (int i = 0; i < 4; i++) {
        async16(abase + i * astep, (char*)At[0] + doff + i * 4096);
        async16(wbase + i * wstep, (char*)Wt[0] + doff + i * 4096);
    }

    for (int k = 0; k < nk; k++) {
        const int b = k & 1;
        __syncthreads();
        if (k + 1 < nk) {
            int k2 = (k + 1) << 6;
#pragma unroll
            for (int i = 0; i < 4; i++) {
                async16(abase + k2 + i * astep, (char*)At[b ^ 1] + doff + i * 4096);
                async16(wbase + k2 + i * wstep, (char*)Wt[b ^ 1] + doff + i * 4096);
            }
        }
        short8 ah[4], al[4];
#pragma unroll
        for (int mi = 0; mi < 4; mi++) {
            int r = wm * 64 + mi * 16 + fr;
            ah[mi] = *(const short8*)&At[b][r * 64 + cph];
            if (NM == 3) al[mi] = *(const short8*)&At[b][r * 64 + cpl];
        }
#pragma unroll
        for (int ni = 0; ni < 4; ni++) {
            int r = wn * 64 + ni * 16 + fr;
            short8 wh8 = *(const short8*)&Wt[b][r * 64 + cph];
            short8 wl8 = *(const short8*)&Wt[b][r * 64 + cpl];
#pragma unroll
            for (int mi = 0; mi < 4; mi++) {
                acc[mi][ni] = __builtin_amdgcn_mfma_f32_16x16x32_bf16(ah[mi], wh8, acc[mi][ni], 0, 0, 0);
                acc[mi][ni] = __builtin_amdgcn_mfma_f32_16x16x32_bf16(ah[mi], wl8, acc[mi][ni], 0, 0, 0);
                if (NM == 3)
                    acc[mi][ni] = __builtin_amdgcn_mfma_f32_16x16x32_bf16(al[mi], wh8, acc[mi][ni], 0, 0, 0);
            }
        }
    }
#pragma unroll
    for (int ni = 0; ni < 4; ni++) {
        int col = n0 + wn * 64 + ni * 16 + fr;
        float bv = bias[col];
#pragma unroll
        for (int mi = 0; mi < 4; mi++) {
            int row = m0 + wm * 64 + mi * 16 + q * 4;
#pragma unroll
            for (int r = 0; r < 4; r++) {
                float v = acc[mi][ni][r] + bv;
                if (RESP) v += sep_load(RsdS, (size_t)(row + r), 2 * ldc, col);
                if (RELU) v = fmaxf(v, 0.f);
                if (OUTP)      sep_store(Cp, (size_t)(row + r), 2 * ldc, col, v);
                else if (OUTB) Cp[(size_t)(row + r) * ldc + col] = bf16rn(v);
                else           Cf[(size_t)(row + r) * ldc + col] = v;
            }
        }
    }
}

// ---------------- single-bf16-A GEMM: C = A*W^T + bias + sep-res --------
// A: plain bf16 [row][K]. LDS A: slot p -> row=p&127, kc=p>>7 (col-major; 2-way free).
// NM=2: A*(W_hi+W_lo).  NM=1: A*W_hi only (output path; A already 2^-8 quantized).
template<int NM, bool RELU, bool RESP>
__global__ __launch_bounds__(256, 2) void gemm_sb(const u16* __restrict__ Ab,
        const u16* __restrict__ Wp, const float* __restrict__ bias,
        const u16* __restrict__ RsdS, float* __restrict__ Cf,
        int ldc, int K, int lda) {
    __shared__ alignas(16) u16 At[2][4096];   // [kc 0..3][row 0..127][8 u16]
    __shared__ alignas(16) u16 Wt[2][8192];
    const int tid = threadIdx.x;
    int linear = blockIdx.y * gridDim.x + blockIdx.x;
    int xcd = linear & 7, sseq = linear >> 3;
    int mper = gridDim.y >> 3;
    int mt = xcd * mper + (sseq % mper);
    int nt = sseq / mper;
    const int m0 = mt * 128, n0 = nt * 128;
    const int lane = tid & 63, wv = tid >> 6;
    const int wm = wv >> 1, wn = wv & 1;
    const int fr = lane & 15, q = lane >> 4;

    floatx4 acc[4][4] = {};

    const int ar = tid & 127;
    const u16* abase = Ab + (size_t)(m0 + ar) * lda + (tid >> 7) * 8;
    const int adoff = tid * 16;   // byte, +i*4096
    const int r0 = tid >> 3;
    const int gc = (tid & 7) ^ (r0 & 7);
    const u16* wbase = Wp + (size_t)(n0 + r0) * (2 * K) + gc * 8;
    const size_t wstep = (size_t)32 * 2 * K;
    const int wdoff = tid * 16;
    const int nk = K >> 5;

    const int cph = ((q << 1) ^ (fr & 7)) << 3;
    const int cpl = ((q << 1) ^ (fr & 7) ^ 1) << 3;

#pragma unroll
    for (int i = 0; i < 2; i++)
        async16(abase + i * 16, (char*)At[0] + adoff + i * 4096);
#pragma unroll
    for (int i = 0; i < 4; i++)
        async16(wbase + i * wstep, (char*)Wt[0] + wdoff + i * 4096);

    for (int k = 0; k < nk; k++) {
        const int b = k & 1;
        __syncthreads();
        if (k + 1 < nk) {
            int ka = (k + 1) << 5;   // u16 elems
            int kw = (k + 1) << 6;
#pragma unroll
            for (int i = 0; i < 2; i++)
                async16(abase + ka + i * 16, (char*)At[b ^ 1] + adoff + i * 4096);
#pragma unroll
            for (int i = 0; i < 4; i++)
                async16(wbase + kw + i * wstep, (char*)Wt[b ^ 1] + wdoff + i * 4096);
        }
        short8 af[4];
#pragma unroll
        for (int mi = 0; mi < 4; mi++) {
            int r = wm * 64 + mi * 16 + fr;
            af[mi] = *(const short8*)&At[b][q * 1024 + r * 8];
        }
#pragma unroll
        for (int ni = 0; ni < 4; ni++) {
            int r = wn * 64 + ni * 16 + fr;
            short8 wh8 = *(const short8*)&Wt[b][r * 64 + cph];
            short8 wl8;
            if (NM == 2) wl8 = *(const short8*)&Wt[b][r * 64 + cpl];
#pragma unroll
            for (int mi = 0; mi < 4; mi++) {
                acc[mi][ni] = __builtin_amdgcn_mfma_f32_16x16x32_bf16(af[mi], wh8, acc[mi][ni], 0, 0, 0);
                if (NM == 2)
                    acc[mi][ni] = __builtin_amdgcn_mfma_f32_16x16x32_bf16(af[mi], wl8, acc[mi][ni], 0, 0, 0);
            }
        }
    }
#pragma unroll
    for (int ni = 0; ni < 4; ni++) {
        int col = n0 + wn * 64 + ni * 16 + fr;
        float bv = bias[col];
#pragma unroll
        for (int mi = 0; mi < 4; mi++) {
            int row = m0 + wm * 64 + mi * 16 + q * 4;
#pragma unroll
            for (int r = 0; r < 4; r++) {
                float v = acc[mi][ni][r] + bv;
                if (RESP) v += sep_load(RsdS, (size_t)(row + r), 2 * ldc, col);
                if (RELU) v = fmaxf(v, 0.f);
                Cf[(size_t)(row + r) * ldc + col] = v;
            }
        }
    }
}

// ---------------- M = max(QK_sample) - sum/L : one wave per (b,h,l) ----------------
__global__ __launch_bounds__(256) void qk_sample_kernel(const float* __restrict__ qkv,
        const int* __restrict__ idx_sample, float* __restrict__ Mout) {
    int r = (blockIdx.x * 256 + threadIdx.x) >> 6;
    int lane = threadIdx.x & 63;
    if (r >= BATCH * NH * SEQ) return;
    int b = r / (NH * SEQ);
    int head = (r / SEQ) % NH;
    int l = r % SEQ;
    int sidx = lane >> 4, dc = lane & 15;
    const float* qrow = qkv + ((size_t)(b * SEQ + l)) * QKVLD + head * HD + dc * 4;
    float4 qf = *(const float4*)qrow;
    int myidx = (lane < NSAMP) ? idx_sample[l * NSAMP + lane] : 0;
    const float* kbase = qkv + (size_t)b * SEQ * QKVLD + 512 + head * HD + dc * 4;
    int kidx[6];
#pragma unroll
    for (int p = 0; p < 6; p++) kidx[p] = __shfl(myidx, p * 4 + sidx);
    float4 kf[6];
#pragma unroll
    for (int p = 0; p < 6; p++) kf[p] = *(const float4*)(kbase + (size_t)kidx[p] * QKVLD);
    float mx = -INFINITY, sm = 0.f;
#pragma unroll
    for (int p = 0; p < 6; p++) {
        float part = qf.x * kf[p].x + qf.y * kf[p].y + qf.z * kf[p].z + qf.w * kf[p].w;
        part += __shfl_xor(part, 1);
        part += __shfl_xor(part, 2);
        part += __shfl_xor(part, 4);
        part += __shfl_xor(part, 8);
        mx = fmaxf(mx, part);
        sm += part;
    }
    mx = fmaxf(mx, __shfl_xor(mx, 16));
    mx = fmaxf(mx, __shfl_xor(mx, 32));
    sm += __shfl_xor(sm, 16);
    sm += __shfl_xor(sm, 32);
    if (lane == 0) Mout[r] = mx - sm * (1.f / SEQ);
}

// ---------------- top-24: register keys + wave shuffle reduce ----------------
__device__ __forceinline__ u64 pack_key(float v, int idx) {
    u32 u = __float_as_uint(v);
    u32 m = (u & 0x80000000u) ? ~u : (u | 0x80000000u);
    return ((u64)m << 32) | (u32)(~(u32)idx);
}

__global__ __launch_bounds__(256) void topk_part(const float* __restrict__ Mbuf,
        u64* __restrict__ cand) {
    __shared__ u64 wred[4];
    int bh = blockIdx.x, chunk = blockIdx.y;
    int tid = threadIdx.x, wv = tid >> 6, lane = tid & 63;
    int l = chunk * 256 + tid;
    u64 val = pack_key(Mbuf[(size_t)bh * SEQ + l], l);
    for (int it = 0; it < NTOP; it++) {
        u64 w = val;
#pragma unroll
        for (int off = 32; off > 0; off >>= 1) {
            u64 o = __shfl_xor(w, off);
            if (o > w) w = o;
        }
        if (lane == 0) wred[wv] = w;
        __syncthreads();
        u64 win = wred[0];
        if (wred[1] > win) win = wred[1];
        if (wred[2] > win) win = wred[2];
        if (wred[3] > win) win = wred[3];
        if (val == win) val = 0;
        if (tid == 0) cand[((size_t)bh * 8 + chunk) * NTOP + it] = win;
        __syncthreads();
    }
}

__global__ __launch_bounds__(256) void topk_merge(const u64* __restrict__ cand,
        int* __restrict__ idx_top) {
    __shared__ u64 wred[4];
    int bh = blockIdx.x;
    int tid = threadIdx.x, wv = tid >> 6, lane = tid & 63;
    u64 val = (tid < 8 * NTOP) ? cand[(size_t)bh * 8 * NTOP + tid] : 0;
    for (int it = 0; it < NTOP; it++) {
        u64 w = val;
#pragma unroll
        for (int off = 32; off > 0; off >>= 1) {
            u64 o = __shfl_xor(w, off);
            if (o > w) w = o;
        }
        if (lane == 0) wred[wv] = w;
        __syncthreads();
        u64 win = wred[0];
        if (wred[1] > win) win = wred[1];
        if (wred[2] > win) win = wred[2];
        if (wred[3] > win) win = wred[3];
        if (val == win) val = 0;
        if (tid == 0) idx_top[bh * NTOP + it] = (int)(~(u32)(win & 0xffffffffull) & (SEQ - 1));
        __syncthreads();
    }
}

// ---------------- V mean over keys per (b,h) ----------------
__global__ __launch_bounds__(256) void vmean_kernel(const float* __restrict__ qkv,
        float* __restrict__ vmean) {
    __shared__ float red[256];
    int bh = blockIdx.x, slab = blockIdx.y;
    int b = bh >> 3, head = bh & 7;
    int seg = threadIdx.x >> 6, d = threadIdx.x & 63;
    int base_row = slab * 256 + seg * 64;
    float s = 0.f;
    for (int r = 0; r < 64; r++)
        s += qkv[((size_t)(b * SEQ + base_row + r)) * QKVLD + 1024 + head * HD + d];
    red[threadIdx.x] = s;
    __syncthreads();
    if (threadIdx.x < 128) red[threadIdx.x] += red[threadIdx.x + 128];
    __syncthreads();
    if (threadIdx.x < 64) {
        float t = red[threadIdx.x] + red[threadIdx.x + 64];
        atomicAdd(&vmean[bh * HD + d], t * (1.f / SEQ));
    }
}

// ---------------- fill context (separated u16) with V-mean: thread = one group ---------
__global__ void fillctx_kernel(const float* __restrict__ vmean, u16* __restrict__ out) {
    int e = blockIdx.x * 256 + threadIdx.x;   // < TOK*64
    int t = e >> 6, g = e & 63;
    const float* vm = vmean + ((((t >> 11) << 3) | (g >> 3)) << 6) + (g & 7) * 8;
    short8 hh, ll;
#pragma unroll
    for (int s = 0; s < 8; s++) {
        float v = vm[s];
        u16 hb = bf16rn(v);
        hh[s] = (short)hb;
        ll[s] = (short)bf16rn(v - __uint_as_float((u32)hb << 16));
    }
    u16* dp = out + (size_t)t * 1024 + g * 16;
    *(short8*)dp = hh;
    *(short8*)(dp + 8) = ll;
}

// ---------------- flash-style sparse attention: block = (b*h, key-slab of 512) ----------------
__global__ __launch_bounds__(256) void spattn_flash(const float* __restrict__ qkv,
        const int* __restrict__ idx_top, float* __restrict__ opart,
        float* __restrict__ mspart) {
    __shared__ float KtT[64][65];   // transposed: [dim][key]
    __shared__ float Vt[64][65];    // [key][dim]
    __shared__ float Qs[24][64];
    __shared__ float Ps[24][66];
    int bh = blockIdx.x, slab = blockIdx.y;
    int b = bh >> 3, h = bh & 7;
    int tid = threadIdx.x;
    int wv = tid >> 6, lane = tid & 63;
    for (int i = tid; i < NTOP * 64; i += 256) {
        int u = i >> 6, d = i & 63;
        int qi = idx_top[bh * NTOP + u];
        Qs[u][d] = qkv[((size_t)(b * SEQ + qi)) * QKVLD + h * HD + d];
    }
    float m[6], s[6], o[6], alpha[6];
#pragma unroll
    for (int j = 0; j < 6; j++) { m[j] = -INFINITY; s[j] = 0.f; o[j] = 0.f; }
    int key0 = slab * 512;
    int sr = tid >> 2, sc0 = (tid & 3) * 16;
    for (int t = 0; t < 8; t++) {
        int kbase = key0 + t * 64;
        __syncthreads();
        const float* kr = qkv + ((size_t)(b * SEQ + kbase + sr)) * QKVLD + 512 + h * HD + sc0;
        const float* vr = qkv + ((size_t)(b * SEQ + kbase + sr)) * QKVLD + 1024 + h * HD + sc0;
        float kf[16], vf[16];
        *(float4*)&kf[0]  = *(const float4*)(kr);
        *(float4*)&kf[4]  = *(const float4*)(kr + 4);
        *(float4*)&kf[8]  = *(const float4*)(kr + 8);
        *(float4*)&kf[12] = *(const float4*)(kr + 12);
        *(float4*)&vf[0]  = *(const float4*)(vr);
        *(float4*)&vf[4]  = *(const float4*)(vr + 4);
        *(float4*)&vf[8]  = *(const float4*)(vr + 8);
        *(float4*)&vf[12] = *(const float4*)(vr + 12);
#pragma unroll
        for (int i = 0; i < 16; i++) {
            KtT[sc0 + i][sr] = kf[i];
            Vt[sr][sc0 + i] = vf[i];
        }
        __syncthreads();
        float dot[6] = {};
#pragma unroll
        for (int d = 0; d < 64; d++) {
            float kv = KtT[d][lane];
#pragma unroll
            for (int j = 0; j < 6; j++) dot[j] += Qs[wv * 6 + j][d] * kv;
        }
#pragma unroll
        for (int j = 0; j < 6; j++) {
            float sc = dot[j] * 0.125f;
            float tmax = sc;
            for (int off = 32; off > 0; off >>= 1) tmax = fmaxf(tmax, __shfl_xor(tmax, off));
            float mn = fmaxf(m[j], tmax);
            float p = __expf(sc - mn);
            float psum = p;
            for (int off = 32; off > 0; off >>= 1) psum += __shfl_xor(psum, off);
            alpha[j] = __expf(m[j] - mn);
            s[j] = s[j] * alpha[j] + psum;
            m[j] = mn;
            Ps[wv * 6 + j][lane] = p;
        }
        float pv[6] = {};
#pragma unroll
        for (int key = 0; key < 64; key++) {
            float vvv = Vt[key][lane];
#pragma unroll
            for (int j = 0; j < 6; j++) pv[j] += Ps[wv * 6 + j][key] * vvv;
        }
#pragma unroll
        for (int j = 0; j < 6; j++) o[j] = o[j] * alpha[j] + pv[j];
    }
    float* ob = opart + ((size_t)(bh * 4 + slab)) * NTOP * 64;
#pragma unroll
    for (int j = 0; j < 6; j++) ob[(wv * 6 + j) * 64 + lane] = o[j];
    if (lane == 0) {
        float* ms = mspart + ((size_t)(bh * 4 + slab)) * NTOP * 2;
#pragma unroll
        for (int j = 0; j < 6; j++) {
            ms[(wv * 6 + j) * 2]     = m[j];
            ms[(wv * 6 + j) * 2 + 1] = s[j];
        }
    }
}

// ---------------- merge 4 slab partials, scatter (separated u16) into context ----------
__global__ __launch_bounds__(256) void spattn_combine(const float* __restrict__ opart,
        const float* __restrict__ mspart, const int* __restrict__ idx_top,
        u16* __restrict__ out) {
    __shared__ float wgt[4][NTOP];
    int bh = blockIdx.x;
    int b = bh >> 3, h = bh & 7;
    int tid = threadIdx.x;
    if (tid < NTOP) {
        float mv[4], sv[4];
        float M = -INFINITY;
#pragma unroll
        for (int sl = 0; sl < 4; sl++) {
            mv[sl] = mspart[((size_t)(bh * 4 + sl)) * NTOP * 2 + tid * 2];
            sv[sl] = mspart[((size_t)(bh * 4 + sl)) * NTOP * 2 + tid * 2 + 1];
            M = fmaxf(M, mv[sl]);
        }
        float S = 0.f;
#pragma unroll
        for (int sl = 0; sl < 4; sl++) S += sv[sl] * __expf(mv[sl] - M);
        float invS = 1.f / S;
#pragma unroll
        for (int sl = 0; sl < 4; sl++) wgt[sl][tid] = __expf(mv[sl] - M) * invS;
    }
    __syncthreads();
    for (int i = tid; i < NTOP * 64; i += 256) {
        int u = i >> 6, d = i & 63;
        float val = 0.f;
#pragma unroll
        for (int sl = 0; sl < 4; sl++)
            val += wgt[sl][u] * opart[(((size_t)(bh * 4 + sl)) * NTOP + u) * 64 + d];
        int qi = idx_top[bh * NTOP + u];
        sep_store(out, (size_t)(b * SEQ + qi), 1024, h * HD + d, val);
    }
}

// ---------------- layernorm over DM=512: one wave per row; sep in/out options ----------
template<bool INP, bool OUTSEP>
__global__ __launch_bounds__(256) void ln_kernel(const float* __restrict__ srcF,
        const u16* __restrict__ srcS, const float* __restrict__ g,
        const float* __restrict__ b, float* __restrict__ dstF, u16* __restrict__ dstS) {
    int wv = threadIdx.x >> 6, lane = threadIdx.x & 63;
    int t = blockIdx.x * 4 + wv;
    float xv[8];
    if (INP) {
        const u16* sp = srcS + (size_t)t * 1024 + (lane >> 1) * 16 + (lane & 1) * 4;
        short4v h0 = *(const short4v*)sp;
        short4v l0 = *(const short4v*)(sp + 8);
        short4v h1 = *(const short4v*)(sp + 512);
        short4v l1 = *(const short4v*)(sp + 520);
#pragma unroll
        for (int i = 0; i < 4; i++) {
            xv[i]     = hl2f((u16)h0[i], (u16)l0[i]);
            xv[i + 4] = hl2f((u16)h1[i], (u16)l1[i]);
        }
    } else {
        float4 x0 = *(const float4*)&srcF[(size_t)t * DM + lane * 4];
        float4 x1 = *(const float4*)&srcF[(size_t)t * DM + lane * 4 + 256];
        xv[0] = x0.x; xv[1] = x0.y; xv[2] = x0.z; xv[3] = x0.w;
        xv[4] = x1.x; xv[5] = x1.y; xv[6] = x1.z; xv[7] = x1.w;
    }
    float s = 0.f, s2 = 0.f;
#pragma unroll
    for (int i = 0; i < 8; i++) { s += xv[i]; s2 += xv[i] * xv[i]; }
#pragma unroll
    for (int off = 32; off > 0; off >>= 1) {
        s  += __shfl_xor(s, off);
        s2 += __shfl_xor(s2, off);
    }
    float m = s * (1.f / DM);
    float var = s2 * (1.f / DM) - m * m;
    float inv = rsqrtf(var + EPS);
    float4 g0 = *(const float4*)&g[lane * 4];
    float4 g1 = *(const float4*)&g[lane * 4 + 256];
    float4 b0 = *(const float4*)&b[lane * 4];
    float4 b1 = *(const float4*)&b[lane * 4 + 256];
    float y[8];
    y[0] = (xv[0] - m) * inv * g0.x + b0.x;  y[1] = (xv[1] - m) * inv * g0.y + b0.y;
    y[2] = (xv[2] - m) * inv * g0.z + b0.z;  y[3] = (xv[3] - m) * inv * g0.w + b0.w;
    y[4] = (xv[4] - m) * inv * g1.x + b1.x;  y[5] = (xv[5] - m) * inv * g1.y + b1.y;
    y[6] = (xv[6] - m) * inv * g1.z + b1.z;  y[7] = (xv[7] - m) * inv * g1.w + b1.w;
    if (OUTSEP) {
        u16* dp = dstS + (size_t)t * 1024 + (lane >> 1) * 16 + (lane & 1) * 4;
        short4v hh0, ll0, hh1, ll1;
#pragma unroll
        for (int i = 0; i < 4; i++) {
            u16 hb = bf16rn(y[i]);
            hh0[i] = (short)hb;
            ll0[i] = (short)bf16rn(y[i] - __uint_as_float((u32)hb << 16));
            u16 hb2 = bf16rn(y[i + 4]);
            hh1[i] = (short)hb2;
            ll1[i] = (short)bf16rn(y[i + 4] - __uint_as_float((u32)hb2 << 16));
        }
        *(short4v*)dp = hh0;
        *(short4v*)(dp + 8) = ll0;
        *(short4v*)(dp + 512) = hh1;
        *(short4v*)(dp + 520) = ll1;
    } else {
        float4 o0 = { y[0], y[1], y[2], y[3] };
        float4 o1 = { y[4], y[5], y[6], y[7] };
        *(float4*)&dstF[(size_t)t * DM + lane * 4] = o0;
        *(float4*)&dstF[(size_t)t * DM + lane * 4 + 256] = o1;
    }
}

// ---------------- prediction head on last token ----------------
__global__ __launch_bounds__(256) void head_kernel(const float* __restrict__ hfin,
        const float* __restrict__ Wpre, const float* __restrict__ bpre,
        const float* __restrict__ Wfc, const float* __restrict__ bfc,
        float* __restrict__ out) {
    __shared__ float last[DM];
    __shared__ float red[256];
    int b = blockIdx.x, tid = threadIdx.x;
    const float* hr = hfin + ((size_t)(b * SEQ + SEQ - 1)) * DM;
    last[tid] = hr[tid];
    last[tid + 256] = hr[tid + 256];
    __syncthreads();
    float acc = bpre[tid];
    for (int c = 0; c < DM; c++) acc += last[c] * Wpre[tid * DM + c];
    acc = fmaxf(acc, 0.f);
    red[tid] = acc * Wfc[tid];
    __syncthreads();
    for (int s = 128; s > 0; s >>= 1) { if (tid < s) red[tid] += red[tid + s]; __syncthreads(); }
    if (tid == 0) out[b] = red[0] + bfc[0];
}

extern "C" void kernel_launch(void* const* d_in, const int* in_sizes, int n_in,
                              void* d_out, int out_size, void* d_ws, size_t ws_size,
                              hipStream_t stream) {
    (void)in_sizes; (void)n_in; (void)out_size; (void)ws_size;
    const float* x      = (const float*)d_in[0];
    const float* tfeat  = (const float*)d_in[1];
    const float* g_in   = (const float*)d_in[2];
    const float* b_in   = (const float*)d_in[3];
    const float* W_tok  = (const float*)d_in[4];
    const float* W_time = (const float*)d_in[5];
    const float* b_time = (const float*)d_in[6];
    const float* Wq     = (const float*)d_in[7];
    const float* bq     = (const float*)d_in[8];
    const float* Wk     = (const float*)d_in[9];
    const float* bk     = (const float*)d_in[10];
    const float* Wv     = (const float*)d_in[11];
    const float* bv     = (const float*)d_in[12];
    const float* Wo     = (const float*)d_in[13];
    const float* bo     = (const float*)d_in[14];
    const float* W1     = (const float*)d_in[15];
    const float* b1     = (const float*)d_in[16];
    const float* W2     = (const float*)d_in[17];
    const float* b2     = (const float*)d_in[18];
    const float* g1     = (const float*)d_in[19];
    const float* be1    = (const float*)d_in[20];
    const float* g2     = (const float*)d_in[21];
    const float* be2    = (const float*)d_in[22];
    const float* g_enc  = (const float*)d_in[23];
    const float* b_enc  = (const float*)d_in[24];
    const float* W_pre  = (const float*)d_in[25];
    const float* b_pre  = (const float*)d_in[26];
    const float* W_fc   = (const float*)d_in[27];
    const float* b_fc   = (const float*)d_in[28];
    float* out = (float*)d_out;

    char* ws = (char*)d_ws;
    u16*   hp   = (u16*)(ws);                        // 33.5 MB residual stream (separated)
    float* hf   = (float*)(ws + 33554432);           // 33.5 MB fp32 scratch
    char*  bigc = ws + 67108864;                     // 134.2 MB multi-use
    float* qkv  = (float*)bigc;                      // [TOK][1536] fp32 (100.7 MB)
    u16*   ctxP = (u16*)(bigc + 100663296);          // attn ctx separated (33.5 MB)
    u16*   midP = (u16*)bigc;                        // FFN mid separated (layer 1)
    u16*   midB = (u16*)bigc;                        // FFN mid plain bf16 (layer 2, 67 MB)
    // embed-stage overlays inside bigc:
    float* xln  = (float*)(bigc);                    // 2 MB
    u16*   acvP = (u16*)(bigc + 2097152);            // im2col separated [TOK][192] u16
    float* pe   = (float*)(bigc + 8388608);          // 4 MB
    u16*   rsdS = (u16*)(bigc + 12582912);           // 33.5 MB
    u16*   wtok = (u16*)(bigc + 46137344);           // W_tok separated [512][192] u16
    u16*   wsep       = (u16*)(ws + 201326592);      // 12.6 MB per-layer weights
    float* Mbuf       = (float*)(ws + 213909504);    // 0.5 MB
    float* vmean      = (float*)(ws + 214433792);
    int*   idx_sample = (int*)(ws + 214450176);
    int*   idx_top    = (int*)(ws + 214843392);
    float* biasqkv    = (float*)(ws + 214849536);
    u64*   cand       = (u64*)(ws + 214855680);      // 98 KB
    float* opart      = (float*)(ws + 214953984);    // 1.57 MB
    float* mspart     = (float*)(ws + 216526848);    // 48 KB

    ln_in_kernel<<<TOK / 256, 256, 0, stream>>>(x, g_in, b_in, xln);
    im2col_kernel<<<TOK, 128, 0, stream>>>(xln, acvP);
    wtok_split<<<192, 256, 0, stream>>>(W_tok, wtok);
    pe_kernel<<<4096, 256, 0, stream>>>(pe);
    rsd_kernel<<<TOK, 256, 0, stream>>>(pe, tfeat, W_time, rsdS);
    sample_kernel<<<dim3(96, 2), 256, 0, stream>>>(idx_sample);

    // conv-as-GEMM: hp = sep(im2col @ W_tok^T + b_time + (pe + time emb))
    gemm_pp<3, false, true, true, false><<<dim3(4, 128), 256, 0, stream>>>(
        acvP, wtok, b_time, rsdS, nullptr, hp, DM, 96, 96);

    const u16* wqkv_p = wsep;                 // rows 0..1535 = Wq;Wk;Wv (K=512)
    const u16* wo_p = wsep + 1572864;
    const u16* w1_p = wsep + 2097152;
    const u16* w2_p = wsep + 4194304;

    for (int li = 0; li < 2; li++) {
        split_weights<<<12288, 256, 0, stream>>>(
            Wq + (size_t)li * DM * DM, Wk + (size_t)li * DM * DM,
            Wv + (size_t)li * DM * DM, Wo + (size_t)li * DM * DM,
            W1 + (size_t)li * DFF * DM, W2 + (size_t)li * DM * DFF, wsep,
            bq + (size_t)li * DM, bk + (size_t)li * DM, bv + (size_t)li * DM, biasqkv);

        const float* bo_i = bo + (size_t)li * DM;
        const float* b1_i = b1 + (size_t)li * DFF;
        const float* b2_i = b2 + (size_t)li * DM;
        const float* g1_i = g1 + (size_t)li * DM;
        const float* be1_i = be1 + (size_t)li * DM;
        const float* g2_i = g2 + (size_t)li * DM;
        const float* be2_i = be2 + (size_t)li * DM;

        // fused QKV: [TOK][1536] fp32 (selection-critical: full 3-MFMA precision)
        gemm_pp<3, false, false, false, false><<<dim3(QKVLD / 128, TOK / 128), 256, 0, stream>>>(
            hp, wqkv_p, biasqkv, nullptr, qkv, nullptr, QKVLD, DM, DM);

        qk_sample_kernel<<<(BATCH * NH * SEQ) / 4, 256, 0, stream>>>(
            qkv, idx_sample + li * SEQ * NSAMP, Mbuf);
        topk_part<<<dim3(BATCH * NH, 8), 256, 0, stream>>>(Mbuf, cand);
        topk_merge<<<BATCH * NH, 256, 0, stream>>>(cand, idx_top);
        hipMemsetAsync(vmean, 0, BATCH * NH * HD * sizeof(float), stream);
        vmean_kernel<<<dim3(BATCH * NH, 8), 256, 0, stream>>>(qkv, vmean);
        fillctx_kernel<<<(TOK * 64) / 256, 256, 0, stream>>>(vmean, ctxP);
        spattn_flash<<<dim3(BATCH * NH, 4), 256, 0, stream>>>(qkv, idx_top, opart, mspart);
        spattn_combine<<<BATCH * NH, 256, 0, stream>>>(opart, mspart, idx_top, ctxP);

        // Wo with sep-residual hp -> fp32 hf (feeds next selection: full precision)
        gemm_pp<3, false, true, false, false><<<dim3(DM / 128, TOK / 128), 256, 0, stream>>>(
            ctxP, wo_p, bo_i, hp, hf, nullptr, DM, DM, DM);
        ln_kernel<false, true><<<TOK / 4, 256, 0, stream>>>(hf, nullptr, g1_i, be1_i, nullptr, hp);

        if (li == 0) {
            // layer-1 FFN: full precision (protects layer-2 ProbSparse selection)
            gemm_pp<3, true, false, true, false><<<dim3(DFF / 128, TOK / 128), 256, 0, stream>>>(
                hp, w1_p, b1_i, nullptr, nullptr, midP, DFF, DM, DM);
            gemm_pp<3, false, true, false, false><<<dim3(DM / 128, TOK / 128), 256, 0, stream>>>(
                midP, w2_p, b2_i, hp, hf, nullptr, DM, DFF, DFF);
        } else {
            // layer-2 FFN: output path only — reduced-MFMA variants.
            // W1-L2: 2-MFMA (A_lo dropped; error << bf16 mid quantization)
            gemm_pp<2, true, false, false, true><<<dim3(DFF / 128, TOK / 128), 256, 0, stream>>>(
                hp, w1_p, b1_i, nullptr, nullptr, midB, DFF, DM, DM);
            // W2-L2: 1-MFMA (W_lo dropped; A already plain bf16)
            gemm_sb<1, false, true><<<dim3(DM / 128, TOK / 128), 256, 0, stream>>>(
                midB, w2_p, b2_i, hp, hf, DM, DFF, DFF);
        }
        ln_kernel<false, true><<<TOK / 4, 256, 0, stream>>>(hf, nullptr, g2_i, be2_i, nullptr, hp);
    }

    ln_kernel<true, false><<<TOK / 4, 256, 0, stream>>>(nullptr, hp, g_enc, b_enc, hf, nullptr);
    head_kernel<<<BATCH, 256, 0, stream>>>(hf, W_pre, b_pre, W_fc, b_fc, out);
}